// Round 12
// baseline (269.408 us; speedup 1.0000x reference)
//
#include <hip/hip_runtime.h>
#include <type_traits>

// ---------- types ----------
typedef short s8v   __attribute__((ext_vector_type(8)));   // 8 x bf16 bits
typedef float f32x4 __attribute__((ext_vector_type(4)));
typedef float f32x16 __attribute__((ext_vector_type(16)));
typedef unsigned int u32x2 __attribute__((ext_vector_type(2)));
typedef unsigned int u32x4 __attribute__((ext_vector_type(4)));

__device__ __forceinline__ unsigned short f2bf(float f) {
    unsigned int u = __builtin_bit_cast(unsigned int, f);
    u += 0x7FFF + ((u >> 16) & 1);          // round-to-nearest-even
    return (unsigned short)(u >> 16);
}
__device__ __forceinline__ float bf2f(unsigned short b) {
    unsigned int u = ((unsigned int)b) << 16;
    return __builtin_bit_cast(float, u);
}
__device__ __forceinline__ unsigned int cvtpk(float lo, float hi) {
    unsigned int w;
    asm("v_cvt_pk_bf16_f32 %0, %1, %2" : "=v"(w) : "v"(lo), "v"(hi));
    return w;
}

__device__ __forceinline__ void gload16(const void* g, void* l) {
    __builtin_amdgcn_global_load_lds(
        (const __attribute__((address_space(1))) void*)g,
        (__attribute__((address_space(3))) void*)l, 16, 0, 0);
}

// ---------- x -> bf16 (vectorized) ----------
__global__ void conv_bf16(const float* __restrict__ src, unsigned short* __restrict__ dst, int n8) {
    int i = blockIdx.x * blockDim.x + threadIdx.x;
    if (i >= n8) return;
    const f32x4* s4 = (const f32x4*)src;
    f32x4 a = s4[2 * i], b = s4[2 * i + 1];
    s8v o;
    o[0] = (short)f2bf(a[0]); o[1] = (short)f2bf(a[1]);
    o[2] = (short)f2bf(a[2]); o[3] = (short)f2bf(a[3]);
    o[4] = (short)f2bf(b[0]); o[5] = (short)f2bf(b[1]);
    o[6] = (short)f2bf(b[2]); o[7] = (short)f2bf(b[3]);
    *(s8v*)(dst + (size_t)i * 8) = o;
}

// ---------- W (KxN f32) -> W^T (NxK bf16), single weight ----------
__global__ void transpose_conv(const float* __restrict__ src, unsigned short* __restrict__ dst,
                               int K, int N) {
    __shared__ float tile[32][33];
    int n0 = blockIdx.x * 32, k0 = blockIdx.y * 32;
    int tx = threadIdx.x, ty = threadIdx.y;     // 32 x 8
#pragma unroll
    for (int r = 0; r < 4; ++r)
        tile[ty + r * 8][tx] = src[(size_t)(k0 + ty + r * 8) * N + n0 + tx];
    __syncthreads();
#pragma unroll
    for (int r = 0; r < 4; ++r)
        dst[(size_t)(n0 + ty + r * 8) * K + k0 + tx] = f2bf(tile[tx][ty + r * 8]);
}

// ---------- wq/wk/wv -> fused W^T [3072][2048] bf16, one launch ----------
__global__ void transpose_conv_qkv(const float* __restrict__ wq, const float* __restrict__ wk,
                                   const float* __restrict__ wv, unsigned short* __restrict__ dst) {
    __shared__ float tile[32][33];
    int n0 = blockIdx.x * 32, k0 = blockIdx.y * 32;   // n0: 0..3071 (out row), k0: 0..2047
    const float* src; int sc, N;
    if (n0 < 2048)      { src = wq; sc = n0;        N = 2048; }
    else if (n0 < 2560) { src = wk; sc = n0 - 2048; N = 512;  }
    else                { src = wv; sc = n0 - 2560; N = 512;  }
    int tx = threadIdx.x, ty = threadIdx.y;     // 32 x 8
#pragma unroll
    for (int r = 0; r < 4; ++r)
        tile[ty + r * 8][tx] = src[(size_t)(k0 + ty + r * 8) * N + sc + tx];
    __syncthreads();
#pragma unroll
    for (int r = 0; r < 4; ++r)
        dst[(size_t)(n0 + ty + r * 8) * 2048 + k0 + tx] = f2bf(tile[tx][ty + r * 8]);
}

// ---------- V (cols 2560..3071 of qkv) -> V^T [b][kvh][128][2048] bf16 ----------
__global__ void vtrans(const unsigned short* __restrict__ qkv, unsigned short* __restrict__ vt) {
    __shared__ unsigned short t[32][33];
    int s0 = blockIdx.x * 32;          // global row 0..4095
    int c0 = blockIdx.y * 32;          // v-col 0..511
    int tx = threadIdx.x, ty = threadIdx.y;   // 32 x 8
#pragma unroll
    for (int r = 0; r < 4; ++r)
        t[ty + r * 8][tx] = qkv[(size_t)(s0 + ty + r * 8) * 3072 + 2560 + c0 + tx];
    __syncthreads();
    int b = s0 >> 11, s = s0 & 2047;
    size_t dbase = (size_t)(b * 4 + (c0 >> 7)) * 128 + (c0 & 127);
#pragma unroll
    for (int r = 0; r < 4; ++r)
        vt[(dbase + ty + r * 8) * 2048 + s + tx] = t[tx][ty + r * 8];
}

// ---------- GEMM (R11 + 2-phase double-buffer): C = A(MxK) * B^T(NxK) ----------
// 128x128 tile, BK=64, 4 waves (2x2, each 64x64 as 2x2 of 32x32 MFMA frags).
// 2-phase: stage NEXT K-tile first, compute current, ONE barrier per K-step
// (catalog minimum-2-phase; R11 version staged-then-waited, exposing full load
// latency each step). LDS 2x32KB double buffer -> 2 blocks/CU.
// 1D grid, XCD-chunked (T1). Staging via global_load_lds w/ unit-XOR swizzle.
// ROPE: fused rotary epilogue + fold 1/sqrt(128) score scale into q columns.
template <typename CT, bool ROPE>
__global__ __launch_bounds__(256)
void gemm_bt(const unsigned short* __restrict__ A, const unsigned short* __restrict__ BT,
             CT* __restrict__ C, const float* __restrict__ fc, const float* __restrict__ fs,
             int M, int N, int K, int ldc) {
    __shared__ unsigned short As[2][128 * 64];
    __shared__ unsigned short Bs[2][128 * 64];
    const int tid = threadIdx.x;
    const int wid = tid >> 6, lane = tid & 63;
    const int l31 = lane & 31, h2 = lane >> 5;
    // T1 XCD swizzle (bijective: nwg%8==0, nbx%8==0)
    const int nbx = N >> 7;                     // column-blocks
    const int per = nbx >> 3;                   // columns per XCD
    const int xcd = blockIdx.x & 7;
    const int li  = blockIdx.x >> 3;
    const int bx  = xcd * per + (li % per);
    const int by  = li / per;
    const int brow = by * 128, bcol = bx * 128;
    const int wr = wid >> 1, wc = wid & 1;      // 2x2 waves, 64x64 each
    f32x16 acc[2][2] = {};

    auto stage = [&](int kt, int bufi) {
#pragma unroll
        for (int i = 0; i < 4; ++i) {           // A,B tiles: 1024 chunks of 16B each
            int c = i * 256 + tid;
            int row = c >> 3, u = c & 7;
            gload16(A + (size_t)(brow + row) * K + kt + ((u ^ (row & 7)) << 3),
                    &As[bufi][(size_t)c * 8]);
            gload16(BT + (size_t)(bcol + row) * K + kt + ((u ^ (row & 7)) << 3),
                    &Bs[bufi][(size_t)c * 8]);
        }
    };

    int cur = 0;
    stage(0, 0);
    __syncthreads();

    for (int kt = 0; kt < K; kt += 64) {
        if (kt + 64 < K) stage(kt + 64, cur ^ 1);
        const unsigned short* Ab = &As[cur][0];
        const unsigned short* Bb = &Bs[cur][0];
        s8v a[2][4], b[2][4];                    // [frag][kstep of 16]
#pragma unroll
        for (int mm = 0; mm < 2; ++mm) {
            int row = wr * 64 + mm * 32 + l31;
#pragma unroll
            for (int ks = 0; ks < 4; ++ks)
                a[mm][ks] = *(const s8v*)(Ab + (size_t)row * 64 +
                                          (((2 * ks + h2) ^ (row & 7)) << 3));
        }
#pragma unroll
        for (int nn = 0; nn < 2; ++nn) {
            int row = wc * 64 + nn * 32 + l31;
#pragma unroll
            for (int ks = 0; ks < 4; ++ks)
                b[nn][ks] = *(const s8v*)(Bb + (size_t)row * 64 +
                                          (((2 * ks + h2) ^ (row & 7)) << 3));
        }
        __builtin_amdgcn_s_setprio(1);
#pragma unroll
        for (int ks = 0; ks < 4; ++ks)
#pragma unroll
            for (int mm = 0; mm < 2; ++mm)
#pragma unroll
                for (int nn = 0; nn < 2; ++nn)
                    acc[mm][nn] = __builtin_amdgcn_mfma_f32_32x32x16_bf16(
                        a[mm][ks], b[nn][ks], acc[mm][nn], 0, 0, 0);
        __builtin_amdgcn_s_setprio(0);
        __syncthreads();
        cur ^= 1;
    }
    // epilogue: D row = mm*32 + (reg&3)+8*(reg>>2)+4*h2, D col = nn*32+l31 (R8-verified)
#pragma unroll
    for (int mm = 0; mm < 2; ++mm)
#pragma unroll
        for (int nn = 0; nn < 2; ++nn)
#pragma unroll
            for (int reg = 0; reg < 16; ++reg) {
                int r = brow + wr * 64 + mm * 32 + (reg & 3) + 8 * (reg >> 2) + 4 * h2;
                int c = bcol + wc * 64 + nn * 32 + l31;
                float v = acc[mm][nn][reg];
                if constexpr (ROPE) {
                    // q cols [0,2048), k cols [2048,2560): rotate pairs (c even, c+1)
                    float vp = __shfl_xor(v, 1);
                    if (c < 2560) {
                        int fi = ((r & 2047) << 6) + ((c & 127) >> 1);
                        float cs = fc[fi], sn = fs[fi];
                        v = (l31 & 1) ? (vp * sn + v * cs) : (v * cs - vp * sn);
                    }
                    if (c < 2048) v *= 0.08838834764831845f;   // fold 1/sqrt(128) into q
                }
                if constexpr (std::is_same<CT, float>::value)
                    C[(size_t)r * ldc + c] = v;
                else
                    C[(size_t)r * ldc + c] = f2bf(v);
            }
}

// ---------- Flash attention (R11 structure — 96.3 us) with pre-scaled q ----------
// 512 blocks x 256 threads (4 waves). blockIdx&7 = (b,kvh) -> XCD-pinned KV.
// qi = 63 - (bid>>3): measured-best (R7 pairing and R9 8-wave merge both regressed).
// Mask-skip: only the last tile intersects the causal diagonal. Score scale is
// pre-folded into q at gemm1 epilogue -> raw sacc used directly.
__global__ __launch_bounds__(256)
void attn_kernel(const unsigned short* __restrict__ qkv,
                 const unsigned short* __restrict__ vtg,
                 unsigned short* __restrict__ out) {
    constexpr int S = 2048;
    __shared__ unsigned short Ks[2][64 * 128];   // [key][d-unit8 ^ (key&7)]
    __shared__ unsigned short Vs[2][128 * 64];   // [d][key-unit8 ^ (d&7)]
    const int tid = threadIdx.x, lane = tid & 63, wid = tid >> 6;
    const int l31 = lane & 31, h2 = lane >> 5;
    const int lsw = l31 & 7;
    const int g8 = blockIdx.x & 7;               // (b,kvh) -> XCD pin
    const int b = g8 >> 2, kvh = g8 & 3;
    const int qi = 63 - (blockIdx.x >> 3);       // measured-best ordering
    const int h = kvh * 4 + wid;                 // wave = head
    const int qw = qi * 32;
    const int qq = qw + l31;                     // this lane's q row
    const size_t rs = 3072;

    const unsigned short* Qp = qkv + (size_t)(b * S + qw) * rs + h * 128 + h2 * 8;
    const unsigned short* Kbase = qkv + (size_t)(b * S) * rs + 2048 + kvh * 128;
    const unsigned short* Vtg = vtg + (size_t)((b * 4 + kvh) * 128) * S;

    // Q B-frag: col=q=l31, k = 16*kk + 8*h2 + e
    s8v qf[8];
#pragma unroll
    for (int kk = 0; kk < 8; ++kk)
        qf[kk] = *(const s8v*)(Qp + (size_t)l31 * rs + kk * 16);

    f32x16 acc[4] = {};                          // out^T: acc[dblk], row d, col q
    float m_run = -1e30f, l_run = 0.f;
    const int nt = (qi >> 1) + 1;

    auto stage = [&](int t, int bufi) {
        const int kb64 = t * 64;
#pragma unroll
        for (int i = 0; i < 4; ++i) {            // K tile [64][128]: 1024 chunks of 16B
            int c = i * 256 + tid;
            int key = c >> 4, d8 = c & 15;
            gload16(Kbase + (size_t)(kb64 + key) * rs + ((d8 ^ (key & 7)) << 3),
                    &Ks[bufi][(size_t)c * 8]);
        }
#pragma unroll
        for (int i = 0; i < 4; ++i) {            // V^T tile [128][64]
            int c = i * 256 + tid;
            int d = c >> 3, k8 = c & 7;
            gload16(Vtg + (size_t)d * S + kb64 + ((k8 ^ (d & 7)) << 3),
                    &Vs[bufi][(size_t)c * 8]);
        }
    };

    int cur = 0;
    stage(0, 0);
    __syncthreads();

    for (int t = 0; t < nt; ++t) {
        if (t + 1 < nt) stage(t + 1, cur ^ 1);
        const int kb64 = t * 64;
        const char* Kb = (const char*)&Ks[cur][0];
        const char* Vb = (const char*)&Vs[cur][0];

        // ---- K A-frags from LDS (row=key, k=16kk+8h2+e); conflict-free swizzled ----
        s8v kf0[8], kf1[8];
#pragma unroll
        for (int kk = 0; kk < 8; ++kk)
            kf0[kk] = *(const s8v*)(Kb + l31 * 256 + (((2 * kk + h2) ^ lsw) << 4));
#pragma unroll
        for (int kk = 0; kk < 8; ++kk)
            kf1[kk] = *(const s8v*)(Kb + (32 + l31) * 256 + (((2 * kk + h2) ^ lsw) << 4));
        // ---- V^T A-frags (row=d=32dblk+l31, k=key=16kb+8h2+e) ----
        s8v vf[4][4];
#pragma unroll
        for (int kb = 0; kb < 4; ++kb)
#pragma unroll
            for (int dblk = 0; dblk < 4; ++dblk)
                vf[kb][dblk] = *(const s8v*)(Vb + (32 * dblk + l31) * 128 +
                                             (((2 * kb + h2) ^ lsw) << 4));

        // ---- QK^T (swapped): S^T[key][q], C col = q lane-local ----
        f32x16 sacc0 = {}, sacc1 = {};
        __builtin_amdgcn_s_setprio(1);
#pragma unroll
        for (int kk = 0; kk < 8; ++kk)
            sacc0 = __builtin_amdgcn_mfma_f32_32x32x16_bf16(kf0[kk], qf[kk], sacc0, 0, 0, 0);
#pragma unroll
        for (int kk = 0; kk < 8; ++kk)
            sacc1 = __builtin_amdgcn_mfma_f32_32x32x16_bf16(kf1[kk], qf[kk], sacc1, 0, 0, 0);
        __builtin_amdgcn_s_setprio(0);

        // ---- scores (q pre-scaled at gemm1); mask only on the diagonal tile ----
        float sv[32];
        if (t == nt - 1) {
#pragma unroll
            for (int g = 0; g < 2; ++g)
#pragma unroll
                for (int r = 0; r < 16; ++r) {
                    int key = kb64 + 32 * g + (r & 3) + 8 * (r >> 2) + 4 * h2;
                    float s = (g ? sacc1[r] : sacc0[r]);
                    sv[g * 16 + r] = (key <= qq) ? s : -1e30f;
                }
        } else {
#pragma unroll
            for (int r = 0; r < 16; ++r) sv[r] = sacc0[r];
#pragma unroll
            for (int r = 0; r < 16; ++r) sv[16 + r] = sacc1[r];
        }

        // ---- online softmax, q lane-local; defer-max (THR=8) ----
        float mx = sv[0];
#pragma unroll
        for (int i = 1; i < 32; ++i) mx = fmaxf(mx, sv[i]);
        mx = fmaxf(mx, __shfl_xor(mx, 32));
        if (!__all(mx - m_run <= 8.f)) {
            float mn = fmaxf(m_run, mx);
            float alpha = __expf(m_run - mn);
            m_run = mn;
            l_run *= alpha;
#pragma unroll
            for (int dblk = 0; dblk < 4; ++dblk)
#pragma unroll
                for (int r = 0; r < 16; ++r) acc[dblk][r] *= alpha;
        }
        float ps = 0.f;
#pragma unroll
        for (int i = 0; i < 32; ++i) {
            float e = __expf(sv[i] - m_run);
            sv[i] = e;
            ps += e;
        }
        ps += __shfl_xor(ps, 32);
        l_run += ps;

        // ---- P -> B-frag (col=q, k=key): cvt_pk pairs + lane^32 exchange ----
        unsigned int pw[4][4];
#pragma unroll
        for (int g = 0; g < 2; ++g) {
            unsigned int w[8];
#pragma unroll
            for (int j = 0; j < 8; ++j)
                w[j] = cvtpk(sv[g * 16 + 2 * j], sv[g * 16 + 2 * j + 1]);
#pragma unroll
            for (int u = 0; u < 2; ++u) {
                unsigned int t0 = (unsigned)__shfl_xor((int)w[4 * u + 0], 32);
                unsigned int t1 = (unsigned)__shfl_xor((int)w[4 * u + 1], 32);
                unsigned int t2 = (unsigned)__shfl_xor((int)w[4 * u + 2], 32);
                unsigned int t3 = (unsigned)__shfl_xor((int)w[4 * u + 3], 32);
                pw[2 * g + u][0] = h2 ? t2 : w[4 * u + 0];
                pw[2 * g + u][1] = h2 ? t3 : w[4 * u + 1];
                pw[2 * g + u][2] = h2 ? w[4 * u + 2] : t0;
                pw[2 * g + u][3] = h2 ? w[4 * u + 3] : t1;
            }
        }

        // ---- PV: out^T[d][q] += V^T(32d x 16k) * P^T(16k x 32q) ----
        __builtin_amdgcn_s_setprio(1);
#pragma unroll
        for (int kb = 0; kb < 4; ++kb) {
            u32x4 wv;
            wv[0] = pw[kb][0]; wv[1] = pw[kb][1]; wv[2] = pw[kb][2]; wv[3] = pw[kb][3];
            s8v pf = __builtin_bit_cast(s8v, wv);
#pragma unroll
            for (int dblk = 0; dblk < 4; ++dblk)
                acc[dblk] = __builtin_amdgcn_mfma_f32_32x32x16_bf16(vf[kb][dblk], pf, acc[dblk], 0, 0, 0);
        }
        __builtin_amdgcn_s_setprio(0);

        __syncthreads();
        cur ^= 1;
    }

    // ---- normalize (lane-local) and store out[q][h*128+d] ----
    float inv = 1.f / l_run;
    unsigned short* Op = out + (size_t)(b * S + qq) * 2048 + h * 128 + 4 * h2;
#pragma unroll
    for (int dblk = 0; dblk < 4; ++dblk)
#pragma unroll
        for (int s = 0; s < 4; ++s) {
            u32x2 wv;
            wv[0] = cvtpk(acc[dblk][4 * s + 0] * inv, acc[dblk][4 * s + 1] * inv);
            wv[1] = cvtpk(acc[dblk][4 * s + 2] * inv, acc[dblk][4 * s + 3] * inv);
            *(u32x2*)(Op + 32 * dblk + 8 * s) = wv;
        }
}

// ---------- launch ----------
extern "C" void kernel_launch(void* const* d_in, const int* in_sizes, int n_in,
                              void* d_out, int out_size, void* d_ws, size_t ws_size,
                              hipStream_t stream) {
    const float* x  = (const float*)d_in[0];
    const float* fc = (const float*)d_in[1];
    const float* fs = (const float*)d_in[2];
    const float* wq = (const float*)d_in[4];
    const float* wk = (const float*)d_in[5];
    const float* wv = (const float*)d_in[6];
    const float* wo = (const float*)d_in[7];
    float* out = (float*)d_out;

    char* ws = (char*)d_ws;
    unsigned short* xb    = (unsigned short*)ws;                               // 16 MB (reused as attn out)
    unsigned short* wqkvT = (unsigned short*)(ws + 16777216);                  // 12 MB (reused as V^T)
    unsigned short* woT   = (unsigned short*)(ws + 16777216 + 12582912);       // 8 MB
    unsigned short* qkvb  = (unsigned short*)(ws + 16777216 + 12582912 + 8388608); // 24 MB
    unsigned short* attnb = xb;
    unsigned short* vtb   = wqkvT;      // V^T [2][4][128][2048] = 4 MB, lives after gemm1

    conv_bf16<<<4096, 256, 0, stream>>>(x, xb, 1048576);
    dim3 tb(32, 8);
    transpose_conv_qkv<<<dim3(96, 64), tb, 0, stream>>>(wq, wk, wv, wqkvT);
    transpose_conv<<<dim3(64, 64), tb, 0, stream>>>(wo, woT, 2048, 2048);
    // gemm1 with fused RoPE + q-scale on q/k columns; 1D XCD-swizzled grid (24x32)
    gemm_bt<unsigned short, true><<<768, 256, 0, stream>>>(
        xb, wqkvT, qkvb, fc, fs, 4096, 3072, 2048, 3072);
    vtrans<<<dim3(128, 16), tb, 0, stream>>>(qkvb, vtb);
    attn_kernel<<<512, 256, 0, stream>>>(qkvb, vtb, attnb);
    // gemm2; 1D XCD-swizzled grid (16x32)
    gemm_bt<float, false><<<512, 256, 0, stream>>>(
        attnb, woT, out, nullptr, nullptr, 4096, 2048, 2048, 2048);
}

// Round 13
// 252.224 us; speedup vs baseline: 1.0681x; 1.0681x over previous
//
#include <hip/hip_runtime.h>
#include <type_traits>

// ---------- types ----------
typedef short s8v   __attribute__((ext_vector_type(8)));   // 8 x bf16 bits
typedef float f32x4 __attribute__((ext_vector_type(4)));
typedef float f32x16 __attribute__((ext_vector_type(16)));
typedef unsigned int u32x2 __attribute__((ext_vector_type(2)));
typedef unsigned int u32x4 __attribute__((ext_vector_type(4)));

__device__ __forceinline__ unsigned short f2bf(float f) {
    unsigned int u = __builtin_bit_cast(unsigned int, f);
    u += 0x7FFF + ((u >> 16) & 1);          // round-to-nearest-even
    return (unsigned short)(u >> 16);
}
__device__ __forceinline__ float bf2f(unsigned short b) {
    unsigned int u = ((unsigned int)b) << 16;
    return __builtin_bit_cast(float, u);
}
__device__ __forceinline__ unsigned int cvtpk(float lo, float hi) {
    unsigned int w;
    asm("v_cvt_pk_bf16_f32 %0, %1, %2" : "=v"(w) : "v"(lo), "v"(hi));
    return w;
}

__device__ __forceinline__ void gload16(const void* g, void* l) {
    __builtin_amdgcn_global_load_lds(
        (const __attribute__((address_space(1))) void*)g,
        (__attribute__((address_space(3))) void*)l, 16, 0, 0);
}

// ---------- merged preprocessing: x->bf16 conv + wq/wk/wv transpose + wo transpose ----------
// One launch, 14336 blocks x 256 threads:
//   [0, 4096)        : conv_bf16 of x (1048576 groups of 8 floats)
//   [4096, 10240)    : transpose_conv of wq/wk/wv -> wqkvT [3072][2048] (grid 96x64)
//   [10240, 14336)   : transpose_conv of wo -> woT [2048][2048] (grid 64x64)
__global__ __launch_bounds__(256)
void prep_kernel(const float* __restrict__ x, const float* __restrict__ wq,
                 const float* __restrict__ wk, const float* __restrict__ wv,
                 const float* __restrict__ wo,
                 unsigned short* __restrict__ xb, unsigned short* __restrict__ wqkvT,
                 unsigned short* __restrict__ woT) {
    __shared__ float tile[32][33];
    const int bid = blockIdx.x;
    if (bid < 4096) {
        int i = bid * 256 + threadIdx.x;
        const f32x4* s4 = (const f32x4*)x;
        f32x4 a = s4[2 * i], b = s4[2 * i + 1];
        s8v o;
        o[0] = (short)f2bf(a[0]); o[1] = (short)f2bf(a[1]);
        o[2] = (short)f2bf(a[2]); o[3] = (short)f2bf(a[3]);
        o[4] = (short)f2bf(b[0]); o[5] = (short)f2bf(b[1]);
        o[6] = (short)f2bf(b[2]); o[7] = (short)f2bf(b[3]);
        *(s8v*)(xb + (size_t)i * 8) = o;
        return;
    }
    const int tx = threadIdx.x & 31, ty = threadIdx.x >> 5;
    const float* src; unsigned short* dst; int sc, N, n0, k0;
    if (bid < 10240) {
        int lb = bid - 4096;
        n0 = (lb % 96) * 32; k0 = (lb / 96) * 32;
        if (n0 < 2048)      { src = wq; sc = n0;        N = 2048; }
        else if (n0 < 2560) { src = wk; sc = n0 - 2048; N = 512;  }
        else                { src = wv; sc = n0 - 2560; N = 512;  }
        dst = wqkvT;
    } else {
        int lb = bid - 10240;
        n0 = (lb % 64) * 32; k0 = (lb / 64) * 32;
        src = wo; sc = n0; N = 2048; dst = woT;
    }
#pragma unroll
    for (int r = 0; r < 4; ++r)
        tile[ty + r * 8][tx] = src[(size_t)(k0 + ty + r * 8) * N + sc + tx];
    __syncthreads();
#pragma unroll
    for (int r = 0; r < 4; ++r)
        dst[(size_t)(n0 + ty + r * 8) * 2048 + k0 + tx] = f2bf(tile[tx][ty + r * 8]);
}

// ---------- V (cols 2560..3071 of qkv) -> V^T [b][kvh][128][2048] bf16 ----------
__global__ void vtrans(const unsigned short* __restrict__ qkv, unsigned short* __restrict__ vt) {
    __shared__ unsigned short t[32][33];
    int s0 = blockIdx.x * 32;          // global row 0..4095
    int c0 = blockIdx.y * 32;          // v-col 0..511
    int tx = threadIdx.x, ty = threadIdx.y;   // 32 x 8
#pragma unroll
    for (int r = 0; r < 4; ++r)
        t[ty + r * 8][tx] = qkv[(size_t)(s0 + ty + r * 8) * 3072 + 2560 + c0 + tx];
    __syncthreads();
    int b = s0 >> 11, s = s0 & 2047;
    size_t dbase = (size_t)(b * 4 + (c0 >> 7)) * 128 + (c0 & 127);
#pragma unroll
    for (int r = 0; r < 4; ++r)
        vt[(dbase + ty + r * 8) * 2048 + s + tx] = t[tx][ty + r * 8];
}

// ---------- GEMM (R11-exact structure; proven fastest): C = A(MxK) * B^T(NxK) ----------
// 128x128 tile, BK=64, 4 waves (2x2, each 64x64 as 2x2 of 32x32 MFMA frags).
// SINGLE 32KB LDS buffer, stage -> barrier -> compute -> barrier. ~5 blocks/CU:
// cross-block overlap of the barrier/vmcnt drain is the load-bearing mechanism
// (R9/R10/R12 all regressed by trading occupancy for per-block pipelining).
// 1D grid, XCD-chunked (T1). Staging via global_load_lds w/ unit-XOR swizzle.
// ROPE: fused rotary epilogue + fold 1/sqrt(128) score scale into q columns.
template <typename CT, bool ROPE>
__global__ __launch_bounds__(256)
void gemm_bt(const unsigned short* __restrict__ A, const unsigned short* __restrict__ BT,
             CT* __restrict__ C, const float* __restrict__ fc, const float* __restrict__ fs,
             int M, int N, int K, int ldc) {
    __shared__ unsigned short As[128 * 64];
    __shared__ unsigned short Bs[128 * 64];
    const int tid = threadIdx.x;
    const int wid = tid >> 6, lane = tid & 63;
    const int l31 = lane & 31, h2 = lane >> 5;
    // T1 XCD swizzle (bijective: nwg%8==0, nbx%8==0)
    const int nbx = N >> 7;                     // column-blocks
    const int per = nbx >> 3;                   // columns per XCD
    const int xcd = blockIdx.x & 7;
    const int li  = blockIdx.x >> 3;
    const int bx  = xcd * per + (li % per);
    const int by  = li / per;
    const int brow = by * 128, bcol = bx * 128;
    const int wr = wid >> 1, wc = wid & 1;      // 2x2 waves, 64x64 each
    f32x16 acc[2][2] = {};

    for (int kt = 0; kt < K; kt += 64) {
#pragma unroll
        for (int i = 0; i < 4; ++i) {           // A,B tiles: 1024 chunks of 16B each
            int c = i * 256 + tid;
            int row = c >> 3, u = c & 7;
            gload16(A + (size_t)(brow + row) * K + kt + ((u ^ (row & 7)) << 3),
                    As + (size_t)c * 8);
            gload16(BT + (size_t)(bcol + row) * K + kt + ((u ^ (row & 7)) << 3),
                    Bs + (size_t)c * 8);
        }
        __syncthreads();
        s8v a[2][4], b[2][4];                    // [frag][kstep of 16]
#pragma unroll
        for (int mm = 0; mm < 2; ++mm) {
            int row = wr * 64 + mm * 32 + l31;
#pragma unroll
            for (int ks = 0; ks < 4; ++ks)
                a[mm][ks] = *(const s8v*)(As + (size_t)row * 64 +
                                          (((2 * ks + h2) ^ (row & 7)) << 3));
        }
#pragma unroll
        for (int nn = 0; nn < 2; ++nn) {
            int row = wc * 64 + nn * 32 + l31;
#pragma unroll
            for (int ks = 0; ks < 4; ++ks)
                b[nn][ks] = *(const s8v*)(Bs + (size_t)row * 64 +
                                          (((2 * ks + h2) ^ (row & 7)) << 3));
        }
#pragma unroll
        for (int ks = 0; ks < 4; ++ks)
#pragma unroll
            for (int mm = 0; mm < 2; ++mm)
#pragma unroll
                for (int nn = 0; nn < 2; ++nn)
                    acc[mm][nn] = __builtin_amdgcn_mfma_f32_32x32x16_bf16(
                        a[mm][ks], b[nn][ks], acc[mm][nn], 0, 0, 0);
        __syncthreads();
    }
    // epilogue: D row = mm*32 + (reg&3)+8*(reg>>2)+4*h2, D col = nn*32+l31 (R8-verified)
#pragma unroll
    for (int mm = 0; mm < 2; ++mm)
#pragma unroll
        for (int nn = 0; nn < 2; ++nn)
#pragma unroll
            for (int reg = 0; reg < 16; ++reg) {
                int r = brow + wr * 64 + mm * 32 + (reg & 3) + 8 * (reg >> 2) + 4 * h2;
                int c = bcol + wc * 64 + nn * 32 + l31;
                float v = acc[mm][nn][reg];
                if constexpr (ROPE) {
                    // q cols [0,2048), k cols [2048,2560): rotate pairs (c even, c+1)
                    float vp = __shfl_xor(v, 1);
                    if (c < 2560) {
                        int fi = ((r & 2047) << 6) + ((c & 127) >> 1);
                        float cs = fc[fi], sn = fs[fi];
                        v = (l31 & 1) ? (vp * sn + v * cs) : (v * cs - vp * sn);
                    }
                    if (c < 2048) v *= 0.08838834764831845f;   // fold 1/sqrt(128) into q
                }
                if constexpr (std::is_same<CT, float>::value)
                    C[(size_t)r * ldc + c] = v;
                else
                    C[(size_t)r * ldc + c] = f2bf(v);
            }
}

// ---------- Flash attention (R12 kernel — pre-scaled q, mask-skip; 96.3us-class) ----------
// 512 blocks x 256 threads (4 waves). blockIdx&7 = (b,kvh) -> XCD-pinned KV.
// qi = 63 - (bid>>3): measured-best (R7 pairing and R9 8-wave merge both regressed).
// Mask-skip: only the last tile intersects the causal diagonal. Score scale is
// pre-folded into q at gemm1 epilogue -> raw sacc used directly.
__global__ __launch_bounds__(256)
void attn_kernel(const unsigned short* __restrict__ qkv,
                 const unsigned short* __restrict__ vtg,
                 unsigned short* __restrict__ out) {
    constexpr int S = 2048;
    __shared__ unsigned short Ks[2][64 * 128];   // [key][d-unit8 ^ (key&7)]
    __shared__ unsigned short Vs[2][128 * 64];   // [d][key-unit8 ^ (d&7)]
    const int tid = threadIdx.x, lane = tid & 63, wid = tid >> 6;
    const int l31 = lane & 31, h2 = lane >> 5;
    const int lsw = l31 & 7;
    const int g8 = blockIdx.x & 7;               // (b,kvh) -> XCD pin
    const int b = g8 >> 2, kvh = g8 & 3;
    const int qi = 63 - (blockIdx.x >> 3);       // measured-best ordering
    const int h = kvh * 4 + wid;                 // wave = head
    const int qw = qi * 32;
    const int qq = qw + l31;                     // this lane's q row
    const size_t rs = 3072;

    const unsigned short* Qp = qkv + (size_t)(b * S + qw) * rs + h * 128 + h2 * 8;
    const unsigned short* Kbase = qkv + (size_t)(b * S) * rs + 2048 + kvh * 128;
    const unsigned short* Vtg = vtg + (size_t)((b * 4 + kvh) * 128) * S;

    // Q B-frag: col=q=l31, k = 16*kk + 8*h2 + e
    s8v qf[8];
#pragma unroll
    for (int kk = 0; kk < 8; ++kk)
        qf[kk] = *(const s8v*)(Qp + (size_t)l31 * rs + kk * 16);

    f32x16 acc[4] = {};                          // out^T: acc[dblk], row d, col q
    float m_run = -1e30f, l_run = 0.f;
    const int nt = (qi >> 1) + 1;

    auto stage = [&](int t, int bufi) {
        const int kb64 = t * 64;
#pragma unroll
        for (int i = 0; i < 4; ++i) {            // K tile [64][128]: 1024 chunks of 16B
            int c = i * 256 + tid;
            int key = c >> 4, d8 = c & 15;
            gload16(Kbase + (size_t)(kb64 + key) * rs + ((d8 ^ (key & 7)) << 3),
                    &Ks[bufi][(size_t)c * 8]);
        }
#pragma unroll
        for (int i = 0; i < 4; ++i) {            // V^T tile [128][64]
            int c = i * 256 + tid;
            int d = c >> 3, k8 = c & 7;
            gload16(Vtg + (size_t)d * S + kb64 + ((k8 ^ (d & 7)) << 3),
                    &Vs[bufi][(size_t)c * 8]);
        }
    };

    int cur = 0;
    stage(0, 0);
    __syncthreads();

    for (int t = 0; t < nt; ++t) {
        if (t + 1 < nt) stage(t + 1, cur ^ 1);
        const int kb64 = t * 64;
        const char* Kb = (const char*)&Ks[cur][0];
        const char* Vb = (const char*)&Vs[cur][0];

        // ---- K A-frags from LDS (row=key, k=16kk+8h2+e); conflict-free swizzled ----
        s8v kf0[8], kf1[8];
#pragma unroll
        for (int kk = 0; kk < 8; ++kk)
            kf0[kk] = *(const s8v*)(Kb + l31 * 256 + (((2 * kk + h2) ^ lsw) << 4));
#pragma unroll
        for (int kk = 0; kk < 8; ++kk)
            kf1[kk] = *(const s8v*)(Kb + (32 + l31) * 256 + (((2 * kk + h2) ^ lsw) << 4));
        // ---- V^T A-frags (row=d=32dblk+l31, k=key=16kb+8h2+e) ----
        s8v vf[4][4];
#pragma unroll
        for (int kb = 0; kb < 4; ++kb)
#pragma unroll
            for (int dblk = 0; dblk < 4; ++dblk)
                vf[kb][dblk] = *(const s8v*)(Vb + (32 * dblk + l31) * 128 +
                                             (((2 * kb + h2) ^ lsw) << 4));

        // ---- QK^T (swapped): S^T[key][q], C col = q lane-local ----
        f32x16 sacc0 = {}, sacc1 = {};
        __builtin_amdgcn_s_setprio(1);
#pragma unroll
        for (int kk = 0; kk < 8; ++kk)
            sacc0 = __builtin_amdgcn_mfma_f32_32x32x16_bf16(kf0[kk], qf[kk], sacc0, 0, 0, 0);
#pragma unroll
        for (int kk = 0; kk < 8; ++kk)
            sacc1 = __builtin_amdgcn_mfma_f32_32x32x16_bf16(kf1[kk], qf[kk], sacc1, 0, 0, 0);
        __builtin_amdgcn_s_setprio(0);

        // ---- scores (q pre-scaled at gemm1); mask only on the diagonal tile ----
        float sv[32];
        if (t == nt - 1) {
#pragma unroll
            for (int g = 0; g < 2; ++g)
#pragma unroll
                for (int r = 0; r < 16; ++r) {
                    int key = kb64 + 32 * g + (r & 3) + 8 * (r >> 2) + 4 * h2;
                    float s = (g ? sacc1[r] : sacc0[r]);
                    sv[g * 16 + r] = (key <= qq) ? s : -1e30f;
                }
        } else {
#pragma unroll
            for (int r = 0; r < 16; ++r) sv[r] = sacc0[r];
#pragma unroll
            for (int r = 0; r < 16; ++r) sv[16 + r] = sacc1[r];
        }

        // ---- online softmax, q lane-local; defer-max (THR=8) ----
        float mx = sv[0];
#pragma unroll
        for (int i = 1; i < 32; ++i) mx = fmaxf(mx, sv[i]);
        mx = fmaxf(mx, __shfl_xor(mx, 32));
        if (!__all(mx - m_run <= 8.f)) {
            float mn = fmaxf(m_run, mx);
            float alpha = __expf(m_run - mn);
            m_run = mn;
            l_run *= alpha;
#pragma unroll
            for (int dblk = 0; dblk < 4; ++dblk)
#pragma unroll
                for (int r = 0; r < 16; ++r) acc[dblk][r] *= alpha;
        }
        float ps = 0.f;
#pragma unroll
        for (int i = 0; i < 32; ++i) {
            float e = __expf(sv[i] - m_run);
            sv[i] = e;
            ps += e;
        }
        ps += __shfl_xor(ps, 32);
        l_run += ps;

        // ---- P -> B-frag (col=q, k=key): cvt_pk pairs + lane^32 exchange ----
        unsigned int pw[4][4];
#pragma unroll
        for (int g = 0; g < 2; ++g) {
            unsigned int w[8];
#pragma unroll
            for (int j = 0; j < 8; ++j)
                w[j] = cvtpk(sv[g * 16 + 2 * j], sv[g * 16 + 2 * j + 1]);
#pragma unroll
            for (int u = 0; u < 2; ++u) {
                unsigned int t0 = (unsigned)__shfl_xor((int)w[4 * u + 0], 32);
                unsigned int t1 = (unsigned)__shfl_xor((int)w[4 * u + 1], 32);
                unsigned int t2 = (unsigned)__shfl_xor((int)w[4 * u + 2], 32);
                unsigned int t3 = (unsigned)__shfl_xor((int)w[4 * u + 3], 32);
                pw[2 * g + u][0] = h2 ? t2 : w[4 * u + 0];
                pw[2 * g + u][1] = h2 ? t3 : w[4 * u + 1];
                pw[2 * g + u][2] = h2 ? w[4 * u + 2] : t0;
                pw[2 * g + u][3] = h2 ? w[4 * u + 3] : t1;
            }
        }

        // ---- PV: out^T[d][q] += V^T(32d x 16k) * P^T(16k x 32q) ----
        __builtin_amdgcn_s_setprio(1);
#pragma unroll
        for (int kb = 0; kb < 4; ++kb) {
            u32x4 wv;
            wv[0] = pw[kb][0]; wv[1] = pw[kb][1]; wv[2] = pw[kb][2]; wv[3] = pw[kb][3];
            s8v pf = __builtin_bit_cast(s8v, wv);
#pragma unroll
            for (int dblk = 0; dblk < 4; ++dblk)
                acc[dblk] = __builtin_amdgcn_mfma_f32_32x32x16_bf16(vf[kb][dblk], pf, acc[dblk], 0, 0, 0);
        }
        __builtin_amdgcn_s_setprio(0);

        __syncthreads();
        cur ^= 1;
    }

    // ---- normalize (lane-local) and store out[q][h*128+d] ----
    float inv = 1.f / l_run;
    unsigned short* Op = out + (size_t)(b * S + qq) * 2048 + h * 128 + 4 * h2;
#pragma unroll
    for (int dblk = 0; dblk < 4; ++dblk)
#pragma unroll
        for (int s = 0; s < 4; ++s) {
            u32x2 wv;
            wv[0] = cvtpk(acc[dblk][4 * s + 0] * inv, acc[dblk][4 * s + 1] * inv);
            wv[1] = cvtpk(acc[dblk][4 * s + 2] * inv, acc[dblk][4 * s + 3] * inv);
            *(u32x2*)(Op + 32 * dblk + 8 * s) = wv;
        }
}

// ---------- launch ----------
extern "C" void kernel_launch(void* const* d_in, const int* in_sizes, int n_in,
                              void* d_out, int out_size, void* d_ws, size_t ws_size,
                              hipStream_t stream) {
    const float* x  = (const float*)d_in[0];
    const float* fc = (const float*)d_in[1];
    const float* fs = (const float*)d_in[2];
    const float* wq = (const float*)d_in[4];
    const float* wk = (const float*)d_in[5];
    const float* wv = (const float*)d_in[6];
    const float* wo = (const float*)d_in[7];
    float* out = (float*)d_out;

    char* ws = (char*)d_ws;
    unsigned short* xb    = (unsigned short*)ws;                               // 16 MB (reused as attn out)
    unsigned short* wqkvT = (unsigned short*)(ws + 16777216);                  // 12 MB (reused as V^T)
    unsigned short* woT   = (unsigned short*)(ws + 16777216 + 12582912);       // 8 MB
    unsigned short* qkvb  = (unsigned short*)(ws + 16777216 + 12582912 + 8388608); // 24 MB
    unsigned short* attnb = xb;
    unsigned short* vtb   = wqkvT;      // V^T [2][4][128][2048] = 4 MB, lives after gemm1

    prep_kernel<<<14336, 256, 0, stream>>>(x, wq, wk, wv, wo, xb, wqkvT, woT);
    // gemm1 with fused RoPE + q-scale on q/k columns; 1D XCD-swizzled grid (24x32)
    gemm_bt<unsigned short, true><<<768, 256, 0, stream>>>(
        xb, wqkvT, qkvb, fc, fs, 4096, 3072, 2048, 3072);
    dim3 tb(32, 8);
    vtrans<<<dim3(128, 16), tb, 0, stream>>>(qkvb, vtb);
    attn_kernel<<<512, 256, 0, stream>>>(qkvb, vtb, attnb);
    // gemm2; 1D XCD-swizzled grid (16x32)
    gemm_bt<float, false><<<512, 256, 0, stream>>>(
        attnb, woT, out, nullptr, nullptr, 4096, 2048, 2048, 2048);
}

// Round 14
// 220.798 us; speedup vs baseline: 1.2202x; 1.1423x over previous
//
#include <hip/hip_runtime.h>
#include <type_traits>

// ---------- types ----------
typedef short s8v   __attribute__((ext_vector_type(8)));   // 8 x bf16 bits
typedef float f32x4 __attribute__((ext_vector_type(4)));
typedef float f32x16 __attribute__((ext_vector_type(16)));
typedef unsigned int u32x2 __attribute__((ext_vector_type(2)));
typedef unsigned int u32x4 __attribute__((ext_vector_type(4)));

__device__ __forceinline__ unsigned short f2bf(float f) {
    unsigned int u = __builtin_bit_cast(unsigned int, f);
    u += 0x7FFF + ((u >> 16) & 1);          // round-to-nearest-even
    return (unsigned short)(u >> 16);
}
__device__ __forceinline__ float bf2f(unsigned short b) {
    unsigned int u = ((unsigned int)b) << 16;
    return __builtin_bit_cast(float, u);
}
__device__ __forceinline__ unsigned int cvtpk(float lo, float hi) {
    unsigned int w;
    asm("v_cvt_pk_bf16_f32 %0, %1, %2" : "=v"(w) : "v"(lo), "v"(hi));
    return w;
}

__device__ __forceinline__ void gload16(const void* g, void* l) {
    __builtin_amdgcn_global_load_lds(
        (const __attribute__((address_space(1))) void*)g,
        (__attribute__((address_space(3))) void*)l, 16, 0, 0);
}

// ---------- merged preprocessing: x->bf16 conv + wq/wk/wv transpose + wo transpose ----------
__global__ __launch_bounds__(256)
void prep_kernel(const float* __restrict__ x, const float* __restrict__ wq,
                 const float* __restrict__ wk, const float* __restrict__ wv,
                 const float* __restrict__ wo,
                 unsigned short* __restrict__ xb, unsigned short* __restrict__ wqkvT,
                 unsigned short* __restrict__ woT) {
    __shared__ float tile[32][33];
    const int bid = blockIdx.x;
    if (bid < 4096) {
        int i = bid * 256 + threadIdx.x;
        const f32x4* s4 = (const f32x4*)x;
        f32x4 a = s4[2 * i], b = s4[2 * i + 1];
        s8v o;
        o[0] = (short)f2bf(a[0]); o[1] = (short)f2bf(a[1]);
        o[2] = (short)f2bf(a[2]); o[3] = (short)f2bf(a[3]);
        o[4] = (short)f2bf(b[0]); o[5] = (short)f2bf(b[1]);
        o[6] = (short)f2bf(b[2]); o[7] = (short)f2bf(b[3]);
        *(s8v*)(xb + (size_t)i * 8) = o;
        return;
    }
    const int tx = threadIdx.x & 31, ty = threadIdx.x >> 5;
    const float* src; unsigned short* dst; int sc, N, n0, k0;
    if (bid < 10240) {
        int lb = bid - 4096;
        n0 = (lb % 96) * 32; k0 = (lb / 96) * 32;
        if (n0 < 2048)      { src = wq; sc = n0;        N = 2048; }
        else if (n0 < 2560) { src = wk; sc = n0 - 2048; N = 512;  }
        else                { src = wv; sc = n0 - 2560; N = 512;  }
        dst = wqkvT;
    } else {
        int lb = bid - 10240;
        n0 = (lb % 64) * 32; k0 = (lb / 64) * 32;
        src = wo; sc = n0; N = 2048; dst = woT;
    }
#pragma unroll
    for (int r = 0; r < 4; ++r)
        tile[ty + r * 8][tx] = src[(size_t)(k0 + ty + r * 8) * N + sc + tx];
    __syncthreads();
#pragma unroll
    for (int r = 0; r < 4; ++r)
        dst[(size_t)(n0 + ty + r * 8) * 2048 + k0 + tx] = f2bf(tile[tx][ty + r * 8]);
}

// ---------- RoPE (standalone, R6-proven coalesced form) + q-scale fold ----------
// In-place on qkvb [4096][3072]; q cols [0,2048) get rope*1/sqrt(128), k cols [2048,2560) rope.
__global__ void rope_kernel(unsigned short* __restrict__ qkv,
                            const float* __restrict__ fc, const float* __restrict__ fs) {
    int idx = blockIdx.x * blockDim.x + threadIdx.x;   // 4096 * 20 * 16
    if (idx >= 4096 * 20 * 16) return;
    int grp = idx & 15;
    int hh = (idx >> 4) % 20;
    int row = idx / (16 * 20);
    int s = row & 2047;
    int col0 = (hh < 16 ? hh * 128 : 2048 + (hh - 16) * 128) + grp * 8;
    unsigned short* p = qkv + (size_t)row * 3072 + col0;
    s8v v = *(const s8v*)p;
    const float* cc = fc + (size_t)s * 64 + grp * 4;
    const float* ss = fs + (size_t)s * 64 + grp * 4;
    const float sc = (hh < 16) ? 0.08838834764831845f : 1.0f;   // fold 1/sqrt(128) into q
#pragma unroll
    for (int j = 0; j < 4; ++j) {
        float xe = bf2f((unsigned short)v[2 * j]);
        float xo = bf2f((unsigned short)v[2 * j + 1]);
        float c = cc[j], sn = ss[j];
        v[2 * j]     = (short)f2bf((xe * c - xo * sn) * sc);
        v[2 * j + 1] = (short)f2bf((xe * sn + xo * c) * sc);
    }
    *(s8v*)p = v;
}

// ---------- V (cols 2560..3071 of qkv) -> V^T [b][kvh][128][2048] bf16 ----------
__global__ void vtrans(const unsigned short* __restrict__ qkv, unsigned short* __restrict__ vt) {
    __shared__ unsigned short t[32][33];
    int s0 = blockIdx.x * 32;          // global row 0..4095
    int c0 = blockIdx.y * 32;          // v-col 0..511
    int tx = threadIdx.x, ty = threadIdx.y;   // 32 x 8
#pragma unroll
    for (int r = 0; r < 4; ++r)
        t[ty + r * 8][tx] = qkv[(size_t)(s0 + ty + r * 8) * 3072 + 2560 + c0 + tx];
    __syncthreads();
    int b = s0 >> 11, s = s0 & 2047;
    size_t dbase = (size_t)(b * 4 + (c0 >> 7)) * 128 + (c0 & 127);
#pragma unroll
    for (int r = 0; r < 4; ++r)
        vt[(dbase + ty + r * 8) * 2048 + s + tx] = t[tx][ty + r * 8];
}

// ---------- GEMM (R11 structure, NO fused epilogue): C = A(MxK) * B^T(NxK) ----------
// 128x128 tile, BK=64, 4 waves (2x2, each 64x64 as 2x2 of 32x32 MFMA frags).
// SINGLE 32KB LDS buffer, stage -> barrier -> compute -> barrier; ~3-5 blocks/CU
// (cross-block drain overlap is load-bearing: R9/R10/R12 all regressed without it).
// R14 experiment: RoPE epilogue REMOVED (cross-round ledger: gemm1 ran 4-5x slower
// per FLOP than gemm2 with 3x FETCH overfetch; the fc/fs gather epilogue is the
// one structural difference). 1D grid, XCD-chunked (T1); unit-XOR LDS swizzle.
template <typename CT>
__global__ __launch_bounds__(256)
void gemm_bt(const unsigned short* __restrict__ A, const unsigned short* __restrict__ BT,
             CT* __restrict__ C, int M, int N, int K, int ldc) {
    __shared__ unsigned short As[128 * 64];
    __shared__ unsigned short Bs[128 * 64];
    const int tid = threadIdx.x;
    const int wid = tid >> 6, lane = tid & 63;
    const int l31 = lane & 31, h2 = lane >> 5;
    // T1 XCD swizzle (bijective: nwg%8==0, nbx%8==0)
    const int nbx = N >> 7;                     // column-blocks
    const int per = nbx >> 3;                   // columns per XCD
    const int xcd = blockIdx.x & 7;
    const int li  = blockIdx.x >> 3;
    const int bx  = xcd * per + (li % per);
    const int by  = li / per;
    const int brow = by * 128, bcol = bx * 128;
    const int wr = wid >> 1, wc = wid & 1;      // 2x2 waves, 64x64 each
    f32x16 acc[2][2] = {};

    for (int kt = 0; kt < K; kt += 64) {
#pragma unroll
        for (int i = 0; i < 4; ++i) {           // A,B tiles: 1024 chunks of 16B each
            int c = i * 256 + tid;
            int row = c >> 3, u = c & 7;
            gload16(A + (size_t)(brow + row) * K + kt + ((u ^ (row & 7)) << 3),
                    As + (size_t)c * 8);
            gload16(BT + (size_t)(bcol + row) * K + kt + ((u ^ (row & 7)) << 3),
                    Bs + (size_t)c * 8);
        }
        __syncthreads();
        s8v a[2][4], b[2][4];                    // [frag][kstep of 16]
#pragma unroll
        for (int mm = 0; mm < 2; ++mm) {
            int row = wr * 64 + mm * 32 + l31;
#pragma unroll
            for (int ks = 0; ks < 4; ++ks)
                a[mm][ks] = *(const s8v*)(As + (size_t)row * 64 +
                                          (((2 * ks + h2) ^ (row & 7)) << 3));
        }
#pragma unroll
        for (int nn = 0; nn < 2; ++nn) {
            int row = wc * 64 + nn * 32 + l31;
#pragma unroll
            for (int ks = 0; ks < 4; ++ks)
                b[nn][ks] = *(const s8v*)(Bs + (size_t)row * 64 +
                                          (((2 * ks + h2) ^ (row & 7)) << 3));
        }
#pragma unroll
        for (int ks = 0; ks < 4; ++ks)
#pragma unroll
            for (int mm = 0; mm < 2; ++mm)
#pragma unroll
                for (int nn = 0; nn < 2; ++nn)
                    acc[mm][nn] = __builtin_amdgcn_mfma_f32_32x32x16_bf16(
                        a[mm][ks], b[nn][ks], acc[mm][nn], 0, 0, 0);
        __syncthreads();
    }
    // epilogue: D row = mm*32 + (reg&3)+8*(reg>>2)+4*h2, D col = nn*32+l31 (R8-verified)
#pragma unroll
    for (int mm = 0; mm < 2; ++mm)
#pragma unroll
        for (int nn = 0; nn < 2; ++nn)
#pragma unroll
            for (int reg = 0; reg < 16; ++reg) {
                int r = brow + wr * 64 + mm * 32 + (reg & 3) + 8 * (reg >> 2) + 4 * h2;
                int c = bcol + wc * 64 + nn * 32 + l31;
                float v = acc[mm][nn][reg];
                if constexpr (std::is_same<CT, float>::value)
                    C[(size_t)r * ldc + c] = v;
                else
                    C[(size_t)r * ldc + c] = f2bf(v);
            }
}

// ---------- Flash attention (R12/R13 kernel — pre-scaled q, mask-skip; ~96us) ----------
// 512 blocks x 256 threads (4 waves). blockIdx&7 = (b,kvh) -> XCD-pinned KV.
// qi = 63 - (bid>>3): measured-best (R7 pairing and R9 8-wave merge both regressed).
// Mask-skip: only the last tile intersects the causal diagonal. Score scale is
// pre-folded into q by rope_kernel -> raw sacc used directly.
__global__ __launch_bounds__(256)
void attn_kernel(const unsigned short* __restrict__ qkv,
                 const unsigned short* __restrict__ vtg,
                 unsigned short* __restrict__ out) {
    constexpr int S = 2048;
    __shared__ unsigned short Ks[2][64 * 128];   // [key][d-unit8 ^ (key&7)]
    __shared__ unsigned short Vs[2][128 * 64];   // [d][key-unit8 ^ (d&7)]
    const int tid = threadIdx.x, lane = tid & 63, wid = tid >> 6;
    const int l31 = lane & 31, h2 = lane >> 5;
    const int lsw = l31 & 7;
    const int g8 = blockIdx.x & 7;               // (b,kvh) -> XCD pin
    const int b = g8 >> 2, kvh = g8 & 3;
    const int qi = 63 - (blockIdx.x >> 3);       // measured-best ordering
    const int h = kvh * 4 + wid;                 // wave = head
    const int qw = qi * 32;
    const int qq = qw + l31;                     // this lane's q row
    const size_t rs = 3072;

    const unsigned short* Qp = qkv + (size_t)(b * S + qw) * rs + h * 128 + h2 * 8;
    const unsigned short* Kbase = qkv + (size_t)(b * S) * rs + 2048 + kvh * 128;
    const unsigned short* Vtg = vtg + (size_t)((b * 4 + kvh) * 128) * S;

    // Q B-frag: col=q=l31, k = 16*kk + 8*h2 + e
    s8v qf[8];
#pragma unroll
    for (int kk = 0; kk < 8; ++kk)
        qf[kk] = *(const s8v*)(Qp + (size_t)l31 * rs + kk * 16);

    f32x16 acc[4] = {};                          // out^T: acc[dblk], row d, col q
    float m_run = -1e30f, l_run = 0.f;
    const int nt = (qi >> 1) + 1;

    auto stage = [&](int t, int bufi) {
        const int kb64 = t * 64;
#pragma unroll
        for (int i = 0; i < 4; ++i) {            // K tile [64][128]: 1024 chunks of 16B
            int c = i * 256 + tid;
            int key = c >> 4, d8 = c & 15;
            gload16(Kbase + (size_t)(kb64 + key) * rs + ((d8 ^ (key & 7)) << 3),
                    &Ks[bufi][(size_t)c * 8]);
        }
#pragma unroll
        for (int i = 0; i < 4; ++i) {            // V^T tile [128][64]
            int c = i * 256 + tid;
            int d = c >> 3, k8 = c & 7;
            gload16(Vtg + (size_t)d * S + kb64 + ((k8 ^ (d & 7)) << 3),
                    &Vs[bufi][(size_t)c * 8]);
        }
    };

    int cur = 0;
    stage(0, 0);
    __syncthreads();

    for (int t = 0; t < nt; ++t) {
        if (t + 1 < nt) stage(t + 1, cur ^ 1);
        const int kb64 = t * 64;
        const char* Kb = (const char*)&Ks[cur][0];
        const char* Vb = (const char*)&Vs[cur][0];

        // ---- K A-frags from LDS (row=key, k=16kk+8h2+e); conflict-free swizzled ----
        s8v kf0[8], kf1[8];
#pragma unroll
        for (int kk = 0; kk < 8; ++kk)
            kf0[kk] = *(const s8v*)(Kb + l31 * 256 + (((2 * kk + h2) ^ lsw) << 4));
#pragma unroll
        for (int kk = 0; kk < 8; ++kk)
            kf1[kk] = *(const s8v*)(Kb + (32 + l31) * 256 + (((2 * kk + h2) ^ lsw) << 4));
        // ---- V^T A-frags (row=d=32dblk+l31, k=key=16kb+8h2+e) ----
        s8v vf[4][4];
#pragma unroll
        for (int kb = 0; kb < 4; ++kb)
#pragma unroll
            for (int dblk = 0; dblk < 4; ++dblk)
                vf[kb][dblk] = *(const s8v*)(Vb + (32 * dblk + l31) * 128 +
                                             (((2 * kb + h2) ^ lsw) << 4));

        // ---- QK^T (swapped): S^T[key][q], C col = q lane-local ----
        f32x16 sacc0 = {}, sacc1 = {};
        __builtin_amdgcn_s_setprio(1);
#pragma unroll
        for (int kk = 0; kk < 8; ++kk)
            sacc0 = __builtin_amdgcn_mfma_f32_32x32x16_bf16(kf0[kk], qf[kk], sacc0, 0, 0, 0);
#pragma unroll
        for (int kk = 0; kk < 8; ++kk)
            sacc1 = __builtin_amdgcn_mfma_f32_32x32x16_bf16(kf1[kk], qf[kk], sacc1, 0, 0, 0);
        __builtin_amdgcn_s_setprio(0);

        // ---- scores (q pre-scaled); mask only on the diagonal tile ----
        float sv[32];
        if (t == nt - 1) {
#pragma unroll
            for (int g = 0; g < 2; ++g)
#pragma unroll
                for (int r = 0; r < 16; ++r) {
                    int key = kb64 + 32 * g + (r & 3) + 8 * (r >> 2) + 4 * h2;
                    float s = (g ? sacc1[r] : sacc0[r]);
                    sv[g * 16 + r] = (key <= qq) ? s : -1e30f;
                }
        } else {
#pragma unroll
            for (int r = 0; r < 16; ++r) sv[r] = sacc0[r];
#pragma unroll
            for (int r = 0; r < 16; ++r) sv[16 + r] = sacc1[r];
        }

        // ---- online softmax, q lane-local; defer-max (THR=8) ----
        float mx = sv[0];
#pragma unroll
        for (int i = 1; i < 32; ++i) mx = fmaxf(mx, sv[i]);
        mx = fmaxf(mx, __shfl_xor(mx, 32));
        if (!__all(mx - m_run <= 8.f)) {
            float mn = fmaxf(m_run, mx);
            float alpha = __expf(m_run - mn);
            m_run = mn;
            l_run *= alpha;
#pragma unroll
            for (int dblk = 0; dblk < 4; ++dblk)
#pragma unroll
                for (int r = 0; r < 16; ++r) acc[dblk][r] *= alpha;
        }
        float ps = 0.f;
#pragma unroll
        for (int i = 0; i < 32; ++i) {
            float e = __expf(sv[i] - m_run);
            sv[i] = e;
            ps += e;
        }
        ps += __shfl_xor(ps, 32);
        l_run += ps;

        // ---- P -> B-frag (col=q, k=key): cvt_pk pairs + lane^32 exchange ----
        unsigned int pw[4][4];
#pragma unroll
        for (int g = 0; g < 2; ++g) {
            unsigned int w[8];
#pragma unroll
            for (int j = 0; j < 8; ++j)
                w[j] = cvtpk(sv[g * 16 + 2 * j], sv[g * 16 + 2 * j + 1]);
#pragma unroll
            for (int u = 0; u < 2; ++u) {
                unsigned int t0 = (unsigned)__shfl_xor((int)w[4 * u + 0], 32);
                unsigned int t1 = (unsigned)__shfl_xor((int)w[4 * u + 1], 32);
                unsigned int t2 = (unsigned)__shfl_xor((int)w[4 * u + 2], 32);
                unsigned int t3 = (unsigned)__shfl_xor((int)w[4 * u + 3], 32);
                pw[2 * g + u][0] = h2 ? t2 : w[4 * u + 0];
                pw[2 * g + u][1] = h2 ? t3 : w[4 * u + 1];
                pw[2 * g + u][2] = h2 ? w[4 * u + 2] : t0;
                pw[2 * g + u][3] = h2 ? w[4 * u + 3] : t1;
            }
        }

        // ---- PV: out^T[d][q] += V^T(32d x 16k) * P^T(16k x 32q) ----
        __builtin_amdgcn_s_setprio(1);
#pragma unroll
        for (int kb = 0; kb < 4; ++kb) {
            u32x4 wv;
            wv[0] = pw[kb][0]; wv[1] = pw[kb][1]; wv[2] = pw[kb][2]; wv[3] = pw[kb][3];
            s8v pf = __builtin_bit_cast(s8v, wv);
#pragma unroll
            for (int dblk = 0; dblk < 4; ++dblk)
                acc[dblk] = __builtin_amdgcn_mfma_f32_32x32x16_bf16(vf[kb][dblk], pf, acc[dblk], 0, 0, 0);
        }
        __builtin_amdgcn_s_setprio(0);

        __syncthreads();
        cur ^= 1;
    }

    // ---- normalize (lane-local) and store out[q][h*128+d] ----
    float inv = 1.f / l_run;
    unsigned short* Op = out + (size_t)(b * S + qq) * 2048 + h * 128 + 4 * h2;
#pragma unroll
    for (int dblk = 0; dblk < 4; ++dblk)
#pragma unroll
        for (int s = 0; s < 4; ++s) {
            u32x2 wv;
            wv[0] = cvtpk(acc[dblk][4 * s + 0] * inv, acc[dblk][4 * s + 1] * inv);
            wv[1] = cvtpk(acc[dblk][4 * s + 2] * inv, acc[dblk][4 * s + 3] * inv);
            *(u32x2*)(Op + 32 * dblk + 8 * s) = wv;
        }
}

// ---------- launch ----------
extern "C" void kernel_launch(void* const* d_in, const int* in_sizes, int n_in,
                              void* d_out, int out_size, void* d_ws, size_t ws_size,
                              hipStream_t stream) {
    const float* x  = (const float*)d_in[0];
    const float* fc = (const float*)d_in[1];
    const float* fs = (const float*)d_in[2];
    const float* wq = (const float*)d_in[4];
    const float* wk = (const float*)d_in[5];
    const float* wv = (const float*)d_in[6];
    const float* wo = (const float*)d_in[7];
    float* out = (float*)d_out;

    char* ws = (char*)d_ws;
    unsigned short* xb    = (unsigned short*)ws;                               // 16 MB (reused as attn out)
    unsigned short* wqkvT = (unsigned short*)(ws + 16777216);                  // 12 MB (reused as V^T)
    unsigned short* woT   = (unsigned short*)(ws + 16777216 + 12582912);       // 8 MB
    unsigned short* qkvb  = (unsigned short*)(ws + 16777216 + 12582912 + 8388608); // 24 MB
    unsigned short* attnb = xb;
    unsigned short* vtb   = wqkvT;      // V^T [2][4][128][2048] = 4 MB, lives after gemm1

    prep_kernel<<<14336, 256, 0, stream>>>(x, wq, wk, wv, wo, xb, wqkvT, woT);
    // gemm1 (plain, no fused epilogue); 1D XCD-swizzled grid (24x32)
    gemm_bt<unsigned short><<<768, 256, 0, stream>>>(
        xb, wqkvT, qkvb, 4096, 3072, 2048, 3072);
    // RoPE + q-scale as standalone coalesced pass (R6-proven ~7us)
    rope_kernel<<<5120, 256, 0, stream>>>(qkvb, fc, fs);
    dim3 tb(32, 8);
    vtrans<<<dim3(128, 16), tb, 0, stream>>>(qkvb, vtb);
    attn_kernel<<<512, 256, 0, stream>>>(qkvb, vtb, attnb);
    // gemm2; 1D XCD-swizzled grid (16x32)
    gemm_bt<float><<<512, 256, 0, stream>>>(
        attnb, woT, out, 4096, 2048, 2048, 2048);
}